// Round 1
// 550.818 us; speedup vs baseline: 1.0967x; 1.0967x over previous
//
#include <hip/hip_runtime.h>
#include <hip/hip_bf16.h>
#include <math.h>

using bf16x8 = __attribute__((ext_vector_type(8))) short;
using f32x4  = __attribute__((ext_vector_type(4))) float;

#define MFMA16(a,b,c) __builtin_amdgcn_mfma_f32_16x16x32_bf16((a),(b),(c),0,0,0)

__device__ __forceinline__ short f2bf(float f){
  union { __hip_bfloat16 h; short s; } u;
  u.h = __float2bfloat16(f);
  return u.s;
}

// async global->LDS, 16B per lane. LDS dest = wave-uniform base + lane*16.
__device__ __forceinline__ void gl_lds16(const void* g, void* l){
  __builtin_amdgcn_global_load_lds(
      (const __attribute__((address_space(1))) unsigned int*)g,
      (__attribute__((address_space(3))) unsigned int*)l, 16, 0, 0);
}

// Problem constants: b=4, q_len=128, H=4096, NH=32, KVH=8, D=128,
// n_qk=n_qv=4096, res=128, past=4224, kv_seq=4352 (= 68 tiles of 64)

// ---------------- 1) cast hidden_states fp32 -> bf16 (512x4096) --------------
__global__ void k_cast_hs(const float* __restrict__ src, short* __restrict__ dst){
  int i = blockIdx.x*256 + threadIdx.x;
  float4 v = reinterpret_cast<const float4*>(src)[i];
  short4 o;
  o.x = f2bf(v.x); o.y = f2bf(v.y); o.z = f2bf(v.z); o.w = f2bf(v.w);
  reinterpret_cast<short4*>(dst)[i] = o;
}

// ---------------- 1b) convert all weights fp32 -> bf16 (one pass) ------------
__global__ void k_conv_w(const float* __restrict__ qw, const float* __restrict__ kw,
                         const float* __restrict__ vw, const float* __restrict__ ow,
                         short* __restrict__ qd, short* __restrict__ kd,
                         short* __restrict__ vd, short* __restrict__ od){
  int bid = blockIdx.x;
  const float* src; short* dst; int rb;
  if (bid < 1024)      { src = qw; dst = qd; rb = bid; }
  else if (bid < 1280) { src = kw; dst = kd; rb = bid - 1024; }
  else if (bid < 1536) { src = vw; dst = vd; rb = bid - 1280; }
  else                 { src = ow; dst = od; rb = bid - 1536; }
  size_t base = (size_t)rb*4096 + threadIdx.x;
  #pragma unroll
  for (int i=0;i<16;++i){
    size_t idx = base + i*256;
    float4 f = reinterpret_cast<const float4*>(src)[idx];
    short4 s;
    s.x=f2bf(f.x); s.y=f2bf(f.y); s.z=f2bf(f.z); s.w=f2bf(f.w);
    reinterpret_cast<short4*>(dst)[idx] = s;
  }
}

// ---------------- 2/8) MFMA GEMM: C = A(bf16) @ B(bf16)^T --------------------
template<int MODE>
__global__ __launch_bounds__(512,1) void k_gemm(
    const short* __restrict__ A,
    const short* __restrict__ B0, const short* __restrict__ B1, const short* __restrict__ B2,
    const float* __restrict__ bias0, const float* __restrict__ bias1, const float* __restrict__ bias2,
    float* __restrict__ Cf)
{
  constexpr int K = 4096;
  constexpr int NSTRIDE = (MODE == 0) ? 6144 : 4096;
  constexpr int NTX = (MODE == 0) ? 6 : 4;      // n-tiles per XCD
  int bid = blockIdx.x;
  int xc = bid & 7, idx = bid >> 3;
  int m_tile = idx & 1, n_tile = xc*NTX + (idx >> 1);
  int mb = m_tile*256, nb = n_tile*128;
  const short* Bsrc = B0; const float* bias = bias0; int nrel = nb;
  if (MODE == 0){
    if (nb >= 5120){ Bsrc = B2; bias = bias2; nrel = nb - 5120; }
    else if (nb >= 4096){ Bsrc = B1; bias = bias1; nrel = nb - 4096; }
  }
  __shared__ short As[2][256*64];   // 32 KB each
  __shared__ short Bs[2][128*64];   // 16 KB each
  int tid = threadIdx.x, w = tid>>6, L = tid&63;
  int lr = L&15, quad = L>>4;
  int wm = (w>>1)*64, wn = (w&1)*64;
  f32x4 acc[4][4] = {};

  auto stage = [&](int buf, int kb){
    #pragma unroll
    for (int i=0;i<4;++i){
      int row = w*32 + i*8 + (L>>3);
      int cl = (L&7) ^ (row&7);
      gl_lds16(A + (size_t)(mb+row)*K + kb + cl*8, &As[buf][(w*32+i*8)*64]);
    }
    #pragma unroll
    for (int i=0;i<2;++i){
      int row = w*16 + i*8 + (L>>3);
      int cl = (L&7) ^ (row&7);
      gl_lds16(Bsrc + (size_t)(nrel+row)*K + kb + cl*8, &Bs[buf][(w*16+i*8)*64]);
    }
  };
  auto compute = [&](int buf){
    #pragma unroll
    for (int kd=0;kd<2;++kd){
      bf16x8 af[4], bfr[4];
      #pragma unroll
      for (int i=0;i<4;++i)
        af[i] = *(const bf16x8*)&As[buf][(wm+i*16+lr)*64 + (((kd*4+quad)^(lr&7))*8)];
      #pragma unroll
      for (int j=0;j<4;++j)
        bfr[j] = *(const bf16x8*)&Bs[buf][(wn+j*16+lr)*64 + (((kd*4+quad)^(lr&7))*8)];
      #pragma unroll
      for (int i=0;i<4;++i)
        #pragma unroll
        for (int j=0;j<4;++j)
          acc[i][j] = MFMA16(af[i], bfr[j], acc[i][j]);
    }
  };

  stage(0, 0);
  __syncthreads();
  for (int s=0; s<64; ++s){
    int cur = s & 1;
    if (s < 63) stage(cur^1, (s+1)*64);
    compute(cur);
    __syncthreads();
  }
  #pragma unroll
  for (int mf=0;mf<4;++mf){
    #pragma unroll
    for (int nf=0;nf<4;++nf){
      int nloc = wn + nf*16 + lr;
      #pragma unroll
      for (int r=0;r<4;++r){
        int row = mb + wm + mf*16 + quad*4 + r;   // C/D: row = quad*4+reg, col = lane&15
        float v = acc[mf][nf][r];
        if (MODE == 0) v += bias[nrel + nloc];
        Cf[(size_t)row*NSTRIDE + nb + nloc] = v;
      }
    }
  }
}

// ---------------- 3) RoPE for Q and K_new, + key_full_past cast --------------
__global__ void k_rope(const float* __restrict__ qkv, const float* __restrict__ kfull,
                       short* __restrict__ Qb, short* __restrict__ Kb)
{
  int bid = blockIdx.x, tid = threadIdx.x;
  const float LOG2_1E6_DIV64 = 0.3114307588956902f;  // log2(1e6)/64
  if (bid < 128){                                     // Q: (b,h) per WG
    int b = bid >> 5, h = bid & 31;
    for (int i=0;i<64;++i){
      int e = i*256 + tid, q = e>>7, d = e&127, fi = d&63;
      float inv = exp2f(-LOG2_1E6_DIV64 * (float)fi);
      float ang = (float)(4224 + q) * inv;
      float sn, cs; sincosf(ang, &sn, &cs);
      const float* row = qkv + (b*128+q)*6144 + h*128;
      float x = row[d], p = row[d^64];
      float o = (d < 64) ? (x*cs - p*sn) : (x*cs + p*sn);
      Qb[((b*32+h)*128 + q)*128 + d] = f2bf(o * 0.12751743f); // log2e/sqrt(128)
    }
  } else if (bid < 160){                              // K_new: (b,kvh) per WG
    int g = bid - 128;                                // g = b*8+kvh
    for (int i=0;i<64;++i){
      int e = i*256 + tid, q = e>>7, d = e&127, fi = d&63;
      float inv = exp2f(-LOG2_1E6_DIV64 * (float)fi);
      float ang = (float)(4224 + q) * inv;
      float sn, cs; sincosf(ang, &sn, &cs);
      const float* row = qkv + ((g>>3)*128+q)*6144 + 4096 + (g&7)*128;
      float x = row[d], p = row[d^64];
      float o = (d < 64) ? (x*cs - p*sn) : (x*cs + p*sn);
      Kb[(g*4352 + 4224 + q)*128 + d] = f2bf(o);
    }
  } else {                                            // key_full_past cast copy
    int g = bid - 160;
    for (int i=0;i<64;++i){
      int e = i*256 + tid, r = e>>7, d = e&127;
      Kb[(g*4352 + 4096 + r)*128 + d] = f2bf(kfull[(g*128 + r)*128 + d]);
    }
  }
}

// ---------------- 4) V transpose: value_full_past & V_new -> Vt[d][n] --------
__global__ void k_vtrans(const float* __restrict__ qkv, const float* __restrict__ vfull,
                         short* __restrict__ Vt)
{
  __shared__ float T[128][132];
  int bid = blockIdx.x;                 // 64 = 32 groups x 2 sources
  int srcsel = bid & 1, g = bid >> 1;   // g = b*8+kvh
  int tid = threadIdx.x;
  for (int i=0;i<64;++i){
    int e = i*256 + tid, r = e>>7, dd = e&127;
    float v;
    if (srcsel == 0) v = vfull[(g*128 + r)*128 + dd];
    else             v = qkv[((g>>3)*128 + r)*6144 + 5120 + (g&7)*128 + dd];
    T[r][dd] = v;
  }
  __syncthreads();
  int n0 = (srcsel == 0) ? 4096 : 4224;
  for (int i=0;i<64;++i){
    int e = i*256 + tid, dd = e>>7, q = e&127;
    Vt[(g*128 + dd)*4352 + n0 + q] = f2bf(T[q][dd]);
  }
}

// ---------------- 5) dequant 2-bit keys -> Kb[n][d] (n<4096) -----------------
__global__ void k_deq_k(const int* __restrict__ kq, const float* __restrict__ ksc,
                        const float* __restrict__ kmn, short* __restrict__ Kb)
{
  __shared__ short KT[64][136];
  int bid = blockIdx.x;                  // 2048 = 32 groups x 64 n-tiles
  int nt = bid & 63, g = bid >> 6;
  int tid = threadIdx.x;
  int d = tid >> 1, half = tid & 1;
  float sc = ksc[(g*128 + d)*64 + nt];
  float mn = kmn[(g*128 + d)*64 + nt];
  #pragma unroll
  for (int j=0;j<2;++j){
    unsigned w = (unsigned)kq[(g*128 + d)*256 + nt*4 + half*2 + j];
    int nbase = (half*2 + j)*16;
    #pragma unroll
    for (int e=0;e<16;++e){
      float v = (float)((w >> (2*e)) & 3u) * sc + mn;
      KT[nbase + e][d] = f2bf(v);
    }
  }
  __syncthreads();
  int n = tid >> 2, c = (tid & 3) * 32;
  const int4* s4 = (const int4*)&KT[n][c];
  int4* d4 = (int4*)(Kb + (g*4352 + nt*64 + n)*128 + c);
  d4[0]=s4[0]; d4[1]=s4[1]; d4[2]=s4[2]; d4[3]=s4[3];
}

// ---------------- 6) dequant 2-bit values -> Vt[d][n] (n<4096) ---------------
__global__ void k_deq_v(const int* __restrict__ vq, const float* __restrict__ vsc,
                        const float* __restrict__ vmn, short* __restrict__ Vt)
{
  __shared__ short VT[128][72];
  int bid = blockIdx.x;                  // 2048
  int nt = bid & 63, g = bid >> 6;
  int tid = threadIdx.x;
  int n = tid >> 2, dp = tid & 3;
  int nglob = nt*64 + n;
  #pragma unroll
  for (int j=0;j<2;++j){
    int dw = dp*2 + j;
    float sc = vsc[(g*4096 + nglob)*2 + (dw>>2)];
    float mn = vmn[(g*4096 + nglob)*2 + (dw>>2)];
    unsigned w = (unsigned)vq[(g*4096 + nglob)*8 + dw];
    #pragma unroll
    for (int e=0;e<16;++e){
      float v = (float)((w >> (2*e)) & 3u) * sc + mn;
      VT[dw*16 + e][n] = f2bf(v);
    }
  }
  __syncthreads();
  int d = tid >> 1, c = (tid & 1) * 32;
  const int4* s4 = (const int4*)&VT[d][c];
  int4* d4 = (int4*)(Vt + (g*128 + d)*4352 + nt*64 + c);
  d4[0]=s4[0]; d4[1]=s4[1]; d4[2]=s4[2]; d4[3]=s4[3];
}

// ---------------- 7) fused flash attention, split-KV (2 blocks/CU) -----------
// Fixed-max softmax (scores bounded) => partial (o, l) over a KV-tile subset
// sum exactly: split each old block's 68 tiles into two blocks of 34 tiles
// each, writing fp32 partials. LDS cut to 72 KB (Q frags loaded straight from
// global; Ps is chunk-XOR-swizzled 64x64 => conflict-free b16 writes AND
// 16B-aligned b128 reads) => 2 blocks/CU, 2 waves/SIMD, independent barrier
// domains per block hide the per-tile DMA-drain + MFMA latency.
__global__ __launch_bounds__(256,2) void k_attn(
    const short* __restrict__ Qb, const short* __restrict__ Kb,
    const short* __restrict__ Vt, float* __restrict__ po, float* __restrict__ lp)
{
  __shared__ short Ks[2][64*128];    // 2 x 16 KB
  __shared__ short Vs[2][128*64];    // 2 x 16 KB
  __shared__ short Ps[64*64];        // 8 KB, chunk-XOR swizzled
  int bid = blockIdx.x;              // 512 = kvh(8) x [split(2) x m(8) x b(4)]
  int kvh = bid & 7, y = bid >> 3;
  int split = y & 1, m = (y >> 1) & 7, b = y >> 4;
  int qt = m & 1, hloc = m >> 1;
  int h = kvh*4 + hloc;
  int g = b*8 + kvh;
  int tid = threadIdx.x, w = tid>>6, L = tid&63;
  int lr = L&15, quad = L>>4;
  const short* kbase = Kb + (size_t)g*4352*128;
  const short* vbase = Vt + (size_t)g*128*4352;

  // Q fragments straight from global (each element read exactly once)
  bf16x8 qf[4];
  {
    const short* qrow = Qb + ((size_t)(b*32+h)*128 + qt*64 + w*16 + lr)*128;
    #pragma unroll
    for (int kd=0;kd<4;++kd)
      qf[kd] = *(const bf16x8*)(qrow + (kd*4+quad)*8);
  }

  auto stageKV = [&](int t, int buf){
    #pragma unroll
    for (int i=0;i<4;++i){
      int row = w*16 + i*4 + (L>>4);
      int cl = (L&15) ^ (row&7);
      gl_lds16(kbase + (size_t)(t*64+row)*128 + cl*8, &Ks[buf][(w*16+i*4)*128]);
    }
    #pragma unroll
    for (int i=0;i<4;++i){
      int row = w*32 + i*8 + (L>>3);
      int cl = (L&7) ^ (row&7);
      gl_lds16(vbase + (size_t)row*4352 + t*64 + cl*8, &Vs[buf][(w*32+i*8)*64]);
    }
  };

  int t0 = split*34;
  stageKV(t0, 0);
  __syncthreads();

  float l_part[4] = {0.f,0.f,0.f,0.f};
  f32x4 o_acc[8] = {};
  int q_glob = qt*64 + w*16 + quad*4;

  for (int ti=0; ti<34; ++ti){
    int t = t0 + ti;
    int cur = ti & 1;
    if (ti < 33) stageKV(t+1, cur^1);
    f32x4 s[4] = {};
    #pragma unroll
    for (int kd=0;kd<4;++kd){
      #pragma unroll
      for (int nt=0;nt<4;++nt){
        bf16x8 kf = *(const bf16x8*)&Ks[cur][(nt*16+lr)*128 + (((kd*4+quad)^(lr&7))*8)];
        s[nt] = MFMA16(qf[kd], kf, s[nt]);
      }
    }
    if (t >= 66){                    // causal mask: cols >= 4224 (split 1 only)
      #pragma unroll
      for (int nt=0;nt<4;++nt){
        int jj = t*64 + nt*16 + lr - 4224;
        #pragma unroll
        for (int r=0;r<4;++r)
          if (jj > q_glob + r) s[nt][r] = -1e30f;
      }
    }
    #pragma unroll
    for (int nt=0;nt<4;++nt){
      #pragma unroll
      for (int r=0;r<4;++r){
        float p = exp2f(s[nt][r]);   // Q pre-scaled by log2e/sqrt(D)
        l_part[r] += p;
        // physical(row,c) = row*64 + ((c>>3 ^ ((row>>2&3)<<1))<<3) + (c&7)
        // here (row>>2)&3 == quad -> conflict-free (8 chunks x 2 same-dword lanes)
        int pc = nt*16 + lr;
        Ps[(w*16 + quad*4 + r)*64 + ((((pc>>3) ^ (quad<<1))<<3)) + (pc&7)] = f2bf(p);
      }
    }
    #pragma unroll
    for (int ks=0;ks<2;++ks){
      // row = w*16+lr -> (row>>2)&3 == lr>>2 ; chunk = ks*4+quad
      bf16x8 a = *(const bf16x8*)&Ps[(w*16+lr)*64 + ((((ks*4+quad) ^ (((lr>>2)&3)<<1)))<<3)];
      #pragma unroll
      for (int dt=0;dt<8;++dt){
        bf16x8 vf = *(const bf16x8*)&Vs[cur][(dt*16+lr)*64 + (((ks*4+quad)^(lr&7))*8)];
        o_acc[dt] = MFMA16(a, vf, o_acc[dt]);
      }
    }
    __syncthreads();                 // buffer rotation + DMA drain (one per tile)
  }
  #pragma unroll
  for (int r=0;r<4;++r){
    #pragma unroll
    for (int off=1; off<16; off<<=1)
      l_part[r] += __shfl_xor(l_part[r], off, 64);
  }
  // write fp32 partials (no divide; combine kernel finishes)
  int prow = (b*32+h)*128 + qt*64 + w*16 + quad*4;
  float* pob = po + (size_t)split*16384*128;
  #pragma unroll
  for (int dt=0;dt<8;++dt)
    #pragma unroll
    for (int r=0;r<4;++r)
      pob[(size_t)(prow + r)*128 + dt*16 + lr] = o_acc[dt][r];
  if (lr == 0){
    #pragma unroll
    for (int r=0;r<4;++r) lp[split*16384 + prow + r] = l_part[r];
  }
}

// ---------------- 7b) combine split-KV partials -> attn bf16 -----------------
__global__ void k_att_comb(const float* __restrict__ po, const float* __restrict__ lp,
                           short* __restrict__ attn)
{
  int i = blockIdx.x*256 + threadIdx.x;   // 524288 threads, 4 floats each
  int row = i >> 5, cp = (i & 31) * 4;    // row = (b*32+h)*128 + q
  float4 a = *(const float4*)(po + (size_t)row*128 + cp);
  float4 c = *(const float4*)(po + (size_t)(16384 + row)*128 + cp);
  float inv = 1.0f / (lp[row] + lp[16384 + row]);
  int bb = row >> 12, hh = (row >> 7) & 31, q = row & 127;
  short4 o;
  o.x = f2bf((a.x + c.x) * inv);
  o.y = f2bf((a.y + c.y) * inv);
  o.z = f2bf((a.z + c.z) * inv);
  o.w = f2bf((a.w + c.w) * inv);
  *(short4*)(attn + (size_t)(bb*128 + q)*4096 + hh*128 + cp) = o;
}

// -----------------------------------------------------------------------------
extern "C" void kernel_launch(void* const* d_in, const int* in_sizes, int n_in,
                              void* d_out, int out_size, void* d_ws, size_t ws_size,
                              hipStream_t stream)
{
  const float* hs  = (const float*)d_in[0];
  const float* q_w = (const float*)d_in[1];
  const float* q_b = (const float*)d_in[2];
  const float* k_w = (const float*)d_in[3];
  const float* k_b = (const float*)d_in[4];
  const float* v_w = (const float*)d_in[5];
  const float* v_b = (const float*)d_in[6];
  const float* o_w = (const float*)d_in[7];
  const int*   kq  = (const int*)d_in[8];
  const float* ksc = (const float*)d_in[9];
  const float* kmn = (const float*)d_in[10];
  const float* kf  = (const float*)d_in[11];
  const int*   vq  = (const int*)d_in[12];
  const float* vsc = (const float*)d_in[13];
  const float* vmn = (const float*)d_in[14];
  const float* vf  = (const float*)d_in[15];

  char* w = (char*)d_ws;
  short* hs_b = (short*)w;  w += (size_t)512*4096*2;        //  4.0 MB
  float* qkv  = (float*)w;  w += (size_t)512*6144*4;        // 12.6 MB
  short* Qb   = (short*)w;  w += (size_t)4*32*128*128*2;    //  4.2 MB
  short* Kb   = (short*)w;  w += (size_t)4*8*4352*128*2;    // 35.7 MB
  short* Vt   = (short*)w;  w += (size_t)4*8*4352*128*2;    // 35.7 MB
  short* attn = (short*)w;  w += (size_t)512*4096*2;        //  4.2 MB
  short* qwb  = (short*)w;  w += (size_t)4096*4096*2;       // 33.6 MB
  short* kwb  = (short*)w;  w += (size_t)1024*4096*2;       //  8.4 MB
  short* vwb  = (short*)w;  w += (size_t)1024*4096*2;       //  8.4 MB
  short* owb  = (short*)w;  w += (size_t)4096*4096*2;       // 33.6 MB (total ~180 MB)

  // split-KV partials alias qwb (dead after k_gemm<0>, 33.6 MB >= 16.9 MB)
  float* po = (float*)qwb;                                  // 2*16384*128*4 = 16.78 MB
  float* lp = (float*)((char*)qwb + (size_t)2*16384*128*4); // 2*16384*4    = 128 KB

  k_cast_hs <<<2048, 256, 0, stream>>>(hs, hs_b);
  k_conv_w  <<<2560, 256, 0, stream>>>(q_w, k_w, v_w, o_w, qwb, kwb, vwb, owb);
  k_gemm<0> <<<96, 512, 0, stream>>>(hs_b, qwb, kwb, vwb, q_b, k_b, v_b, qkv);
  k_rope    <<<192,  256, 0, stream>>>(qkv, kf, Qb, Kb);
  k_vtrans  <<<64,   256, 0, stream>>>(qkv, vf, Vt);
  k_deq_k   <<<2048, 256, 0, stream>>>(kq, ksc, kmn, Kb);
  k_deq_v   <<<2048, 256, 0, stream>>>(vq, vsc, vmn, Vt);
  k_attn    <<<512,  256, 0, stream>>>(Qb, Kb, Vt, po, lp);
  k_att_comb<<<2048, 256, 0, stream>>>(po, lp, attn);
  k_gemm<1> <<<64,   512, 0, stream>>>(attn, owb, nullptr, nullptr,
                                       nullptr, nullptr, nullptr, (float*)d_out);
}

// Round 2
// 451.480 us; speedup vs baseline: 1.3380x; 1.2200x over previous
//
#include <hip/hip_runtime.h>
#include <hip/hip_bf16.h>
#include <math.h>

using bf16x8 = __attribute__((ext_vector_type(8))) short;
using f32x4  = __attribute__((ext_vector_type(4))) float;

#define MFMA16(a,b,c) __builtin_amdgcn_mfma_f32_16x16x32_bf16((a),(b),(c),0,0,0)

__device__ __forceinline__ short f2bf(float f){
  union { __hip_bfloat16 h; short s; } u;
  u.h = __float2bfloat16(f);
  return u.s;
}

// async global->LDS, 16B per lane. LDS dest = wave-uniform base + lane*16.
__device__ __forceinline__ void gl_lds16(const void* g, void* l){
  __builtin_amdgcn_global_load_lds(
      (const __attribute__((address_space(1))) unsigned int*)g,
      (__attribute__((address_space(3))) unsigned int*)l, 16, 0, 0);
}

// Problem constants: b=4, q_len=128, H=4096, NH=32, KVH=8, D=128,
// n_qk=n_qv=4096, res=128, past=4224, kv_seq=4352 (= 68 tiles of 64)

// ---------------- 1) cast hidden_states fp32 -> bf16 (512x4096) --------------
__global__ void k_cast_hs(const float* __restrict__ src, short* __restrict__ dst){
  int i = blockIdx.x*256 + threadIdx.x;
  float4 v = reinterpret_cast<const float4*>(src)[i];
  short4 o;
  o.x = f2bf(v.x); o.y = f2bf(v.y); o.z = f2bf(v.z); o.w = f2bf(v.w);
  reinterpret_cast<short4*>(dst)[i] = o;
}

// ---------------- 1b) convert all weights fp32 -> bf16 (one pass) ------------
__global__ void k_conv_w(const float* __restrict__ qw, const float* __restrict__ kw,
                         const float* __restrict__ vw, const float* __restrict__ ow,
                         short* __restrict__ qd, short* __restrict__ kd,
                         short* __restrict__ vd, short* __restrict__ od){
  int bid = blockIdx.x;
  const float* src; short* dst; int rb;
  if (bid < 1024)      { src = qw; dst = qd; rb = bid; }
  else if (bid < 1280) { src = kw; dst = kd; rb = bid - 1024; }
  else if (bid < 1536) { src = vw; dst = vd; rb = bid - 1280; }
  else                 { src = ow; dst = od; rb = bid - 1536; }
  size_t base = (size_t)rb*4096 + threadIdx.x;
  #pragma unroll
  for (int i=0;i<16;++i){
    size_t idx = base + i*256;
    float4 f = reinterpret_cast<const float4*>(src)[idx];
    short4 s;
    s.x=f2bf(f.x); s.y=f2bf(f.y); s.z=f2bf(f.z); s.w=f2bf(f.w);
    reinterpret_cast<short4*>(dst)[idx] = s;
  }
}

// ---------------- 2/8) MFMA GEMM: C = A(bf16) @ B(bf16)^T, split-K=4 ---------
// 128x128 tile, BK=64, 256 threads (4 waves of 64x64), double-buffered LDS
// (64 KB -> 2 blocks/CU, independent barrier domains), XOR-chunk swizzle.
// Split-K partitions K=4096 into 4 ranges of 1024 (16 K-steps); fp32 partials
// are summed (+bias) by k_comb. Grid: MODE0 = 768 blocks, MODE1 = 512 blocks.
// XCD swizzle: bid&7 = xcd; all m/split blocks of an n-column share the XCD.
template<int MODE>
__global__ __launch_bounds__(256,2) void k_gemm(
    const short* __restrict__ A,
    const short* __restrict__ B0, const short* __restrict__ B1, const short* __restrict__ B2,
    float* __restrict__ P)
{
  constexpr int K = 4096;
  constexpr int NST = (MODE == 0) ? 6144 : 4096;
  constexpr int NTX = (MODE == 0) ? 6 : 4;      // n-tiles per XCD
  int bid = blockIdx.x;
  int xc = bid & 7, idx = bid >> 3;
  int m_tile = idx & 3, split = (idx >> 2) & 3, nl = idx >> 4;
  int n_tile = xc*NTX + nl;
  int mb = m_tile*128, nb = n_tile*128;
  const short* Bsrc = B0; int nrel = nb;
  if (MODE == 0){
    if (nb >= 5120){ Bsrc = B2; nrel = nb - 5120; }
    else if (nb >= 4096){ Bsrc = B1; nrel = nb - 4096; }
  }
  __shared__ short As[2][128*64];   // 16 KB each
  __shared__ short Bs[2][128*64];   // 16 KB each
  int tid = threadIdx.x, w = tid>>6, L = tid&63;
  int lr = L&15, quad = L>>4;
  int wm = (w>>1)*64, wn = (w&1)*64;
  f32x4 acc[4][4] = {};
  int kb0 = split*1024;

  auto stage = [&](int buf, int kb){
    #pragma unroll
    for (int i=0;i<4;++i){
      int row = w*32 + i*8 + (L>>3);
      int cl = (L&7) ^ (row&7);
      gl_lds16(A    + (size_t)(mb  +row)*K + kb + cl*8, &As[buf][(w*32+i*8)*64]);
      gl_lds16(Bsrc + (size_t)(nrel+row)*K + kb + cl*8, &Bs[buf][(w*32+i*8)*64]);
    }
  };
  auto compute = [&](int buf){
    #pragma unroll
    for (int kd=0;kd<2;++kd){
      bf16x8 af[4], bfr[4];
      #pragma unroll
      for (int i=0;i<4;++i)
        af[i] = *(const bf16x8*)&As[buf][(wm+i*16+lr)*64 + (((kd*4+quad)^(lr&7))*8)];
      #pragma unroll
      for (int j=0;j<4;++j)
        bfr[j] = *(const bf16x8*)&Bs[buf][(wn+j*16+lr)*64 + (((kd*4+quad)^(lr&7))*8)];
      #pragma unroll
      for (int i=0;i<4;++i)
        #pragma unroll
        for (int j=0;j<4;++j)
          acc[i][j] = MFMA16(af[i], bfr[j], acc[i][j]);
    }
  };

  stage(0, kb0);
  __syncthreads();
  for (int s=0; s<16; ++s){
    int cur = s & 1;
    if (s < 15) stage(cur^1, kb0 + (s+1)*64);
    compute(cur);
    __syncthreads();
  }
  #pragma unroll
  for (int mf=0;mf<4;++mf){
    #pragma unroll
    for (int nf=0;nf<4;++nf){
      int col = nb + wn + nf*16 + lr;
      #pragma unroll
      for (int r=0;r<4;++r){
        int row = mb + wm + mf*16 + quad*4 + r;   // C/D: row = quad*4+reg, col = lane&15
        P[((size_t)(split*512 + row))*NST + col] = acc[mf][nf][r];
      }
    }
  }
}

// ---------------- 2b/8b) combine split-K partials (+bias for MODE 0) ---------
template<int MODE>
__global__ void k_comb(const float* __restrict__ P, const float* __restrict__ qb,
                       const float* __restrict__ kb, const float* __restrict__ vb,
                       float* __restrict__ O)
{
  constexpr int NST = (MODE == 0) ? 6144 : 4096;
  constexpr int NC  = NST/4;
  int i = blockIdx.x*256 + threadIdx.x;
  int row = i / NC, cp = (i % NC)*4;
  size_t off = (size_t)row*NST + cp;
  constexpr size_t SS = (size_t)512*NST;
  float4 a = *(const float4*)(P + off);
  float4 b2 = *(const float4*)(P + off + SS);
  float4 c = *(const float4*)(P + off + 2*SS);
  float4 d = *(const float4*)(P + off + 3*SS);
  float4 s;
  s.x = a.x+b2.x+c.x+d.x; s.y = a.y+b2.y+c.y+d.y;
  s.z = a.z+b2.z+c.z+d.z; s.w = a.w+b2.w+c.w+d.w;
  if (MODE == 0){
    const float* bs; int bc;
    if (cp < 4096){ bs = qb; bc = cp; }
    else if (cp < 5120){ bs = kb; bc = cp - 4096; }
    else { bs = vb; bc = cp - 5120; }
    float4 bv = *(const float4*)(bs + bc);
    s.x += bv.x; s.y += bv.y; s.z += bv.z; s.w += bv.w;
  }
  *(float4*)(O + off) = s;
}

// ---------------- 3) RoPE for Q and K_new, + key_full_past cast --------------
__global__ void k_rope(const float* __restrict__ qkv, const float* __restrict__ kfull,
                       short* __restrict__ Qb, short* __restrict__ Kb)
{
  int bid = blockIdx.x, tid = threadIdx.x;
  const float LOG2_1E6_DIV64 = 0.3114307588956902f;  // log2(1e6)/64
  if (bid < 128){                                     // Q: (b,h) per WG
    int b = bid >> 5, h = bid & 31;
    for (int i=0;i<64;++i){
      int e = i*256 + tid, q = e>>7, d = e&127, fi = d&63;
      float inv = exp2f(-LOG2_1E6_DIV64 * (float)fi);
      float ang = (float)(4224 + q) * inv;
      float sn, cs; sincosf(ang, &sn, &cs);
      const float* row = qkv + (b*128+q)*6144 + h*128;
      float x = row[d], p = row[d^64];
      float o = (d < 64) ? (x*cs - p*sn) : (x*cs + p*sn);
      Qb[((b*32+h)*128 + q)*128 + d] = f2bf(o * 0.12751743f); // log2e/sqrt(128)
    }
  } else if (bid < 160){                              // K_new: (b,kvh) per WG
    int g = bid - 128;                                // g = b*8+kvh
    for (int i=0;i<64;++i){
      int e = i*256 + tid, q = e>>7, d = e&127, fi = d&63;
      float inv = exp2f(-LOG2_1E6_DIV64 * (float)fi);
      float ang = (float)(4224 + q) * inv;
      float sn, cs; sincosf(ang, &sn, &cs);
      const float* row = qkv + ((g>>3)*128+q)*6144 + 4096 + (g&7)*128;
      float x = row[d], p = row[d^64];
      float o = (d < 64) ? (x*cs - p*sn) : (x*cs + p*sn);
      Kb[(g*4352 + 4224 + q)*128 + d] = f2bf(o);
    }
  } else {                                            // key_full_past cast copy
    int g = bid - 160;
    for (int i=0;i<64;++i){
      int e = i*256 + tid, r = e>>7, d = e&127;
      Kb[(g*4352 + 4096 + r)*128 + d] = f2bf(kfull[(g*128 + r)*128 + d]);
    }
  }
}

// ---------------- 4) V transpose: value_full_past & V_new -> Vt[d][n] --------
__global__ void k_vtrans(const float* __restrict__ qkv, const float* __restrict__ vfull,
                         short* __restrict__ Vt)
{
  __shared__ float T[128][132];
  int bid = blockIdx.x;                 // 64 = 32 groups x 2 sources
  int srcsel = bid & 1, g = bid >> 1;   // g = b*8+kvh
  int tid = threadIdx.x;
  for (int i=0;i<64;++i){
    int e = i*256 + tid, r = e>>7, dd = e&127;
    float v;
    if (srcsel == 0) v = vfull[(g*128 + r)*128 + dd];
    else             v = qkv[((g>>3)*128 + r)*6144 + 5120 + (g&7)*128 + dd];
    T[r][dd] = v;
  }
  __syncthreads();
  int n0 = (srcsel == 0) ? 4096 : 4224;
  for (int i=0;i<64;++i){
    int e = i*256 + tid, dd = e>>7, q = e&127;
    Vt[(g*128 + dd)*4352 + n0 + q] = f2bf(T[q][dd]);
  }
}

// ---------------- 5) dequant 2-bit keys -> Kb[n][d] (n<4096) -----------------
__global__ void k_deq_k(const int* __restrict__ kq, const float* __restrict__ ksc,
                        const float* __restrict__ kmn, short* __restrict__ Kb)
{
  __shared__ short KT[64][136];
  int bid = blockIdx.x;                  // 2048 = 32 groups x 64 n-tiles
  int nt = bid & 63, g = bid >> 6;
  int tid = threadIdx.x;
  int d = tid >> 1, half = tid & 1;
  float sc = ksc[(g*128 + d)*64 + nt];
  float mn = kmn[(g*128 + d)*64 + nt];
  #pragma unroll
  for (int j=0;j<2;++j){
    unsigned w = (unsigned)kq[(g*128 + d)*256 + nt*4 + half*2 + j];
    int nbase = (half*2 + j)*16;
    #pragma unroll
    for (int e=0;e<16;++e){
      float v = (float)((w >> (2*e)) & 3u) * sc + mn;
      KT[nbase + e][d] = f2bf(v);
    }
  }
  __syncthreads();
  int n = tid >> 2, c = (tid & 3) * 32;
  const int4* s4 = (const int4*)&KT[n][c];
  int4* d4 = (int4*)(Kb + (g*4352 + nt*64 + n)*128 + c);
  d4[0]=s4[0]; d4[1]=s4[1]; d4[2]=s4[2]; d4[3]=s4[3];
}

// ---------------- 6) dequant 2-bit values -> Vt[d][n] (n<4096) ---------------
__global__ void k_deq_v(const int* __restrict__ vq, const float* __restrict__ vsc,
                        const float* __restrict__ vmn, short* __restrict__ Vt)
{
  __shared__ short VT[128][72];
  int bid = blockIdx.x;                  // 2048
  int nt = bid & 63, g = bid >> 6;
  int tid = threadIdx.x;
  int n = tid >> 2, dp = tid & 3;
  int nglob = nt*64 + n;
  #pragma unroll
  for (int j=0;j<2;++j){
    int dw = dp*2 + j;
    float sc = vsc[(g*4096 + nglob)*2 + (dw>>2)];
    float mn = vmn[(g*4096 + nglob)*2 + (dw>>2)];
    unsigned w = (unsigned)vq[(g*4096 + nglob)*8 + dw];
    #pragma unroll
    for (int e=0;e<16;++e){
      float v = (float)((w >> (2*e)) & 3u) * sc + mn;
      VT[dw*16 + e][n] = f2bf(v);
    }
  }
  __syncthreads();
  int d = tid >> 1, c = (tid & 1) * 32;
  const int4* s4 = (const int4*)&VT[d][c];
  int4* d4 = (int4*)(Vt + (g*128 + d)*4352 + nt*64 + c);
  d4[0]=s4[0]; d4[1]=s4[1]; d4[2]=s4[2]; d4[3]=s4[3];
}

// ---------------- 7) fused flash attention, split-KV (2 blocks/CU) -----------
__global__ __launch_bounds__(256,2) void k_attn(
    const short* __restrict__ Qb, const short* __restrict__ Kb,
    const short* __restrict__ Vt, float* __restrict__ po, float* __restrict__ lp)
{
  __shared__ short Ks[2][64*128];    // 2 x 16 KB
  __shared__ short Vs[2][128*64];    // 2 x 16 KB
  __shared__ short Ps[64*64];        // 8 KB, chunk-XOR swizzled
  int bid = blockIdx.x;              // 512 = kvh(8) x [split(2) x m(8) x b(4)]
  int kvh = bid & 7, y = bid >> 3;
  int split = y & 1, m = (y >> 1) & 7, b = y >> 4;
  int qt = m & 1, hloc = m >> 1;
  int h = kvh*4 + hloc;
  int g = b*8 + kvh;
  int tid = threadIdx.x, w = tid>>6, L = tid&63;
  int lr = L&15, quad = L>>4;
  const short* kbase = Kb + (size_t)g*4352*128;
  const short* vbase = Vt + (size_t)g*128*4352;

  // Q fragments straight from global (each element read exactly once)
  bf16x8 qf[4];
  {
    const short* qrow = Qb + ((size_t)(b*32+h)*128 + qt*64 + w*16 + lr)*128;
    #pragma unroll
    for (int kd=0;kd<4;++kd)
      qf[kd] = *(const bf16x8*)(qrow + (kd*4+quad)*8);
  }

  auto stageKV = [&](int t, int buf){
    #pragma unroll
    for (int i=0;i<4;++i){
      int row = w*16 + i*4 + (L>>4);
      int cl = (L&15) ^ (row&7);
      gl_lds16(kbase + (size_t)(t*64+row)*128 + cl*8, &Ks[buf][(w*16+i*4)*128]);
    }
    #pragma unroll
    for (int i=0;i<4;++i){
      int row = w*32 + i*8 + (L>>3);
      int cl = (L&7) ^ (row&7);
      gl_lds16(vbase + (size_t)row*4352 + t*64 + cl*8, &Vs[buf][(w*32+i*8)*64]);
    }
  };

  int t0 = split*34;
  stageKV(t0, 0);
  __syncthreads();

  float l_part[4] = {0.f,0.f,0.f,0.f};
  f32x4 o_acc[8] = {};
  int q_glob = qt*64 + w*16 + quad*4;

  for (int ti=0; ti<34; ++ti){
    int t = t0 + ti;
    int cur = ti & 1;
    if (ti < 33) stageKV(t+1, cur^1);
    f32x4 s[4] = {};
    #pragma unroll
    for (int kd=0;kd<4;++kd){
      #pragma unroll
      for (int nt=0;nt<4;++nt){
        bf16x8 kf = *(const bf16x8*)&Ks[cur][(nt*16+lr)*128 + (((kd*4+quad)^(lr&7))*8)];
        s[nt] = MFMA16(qf[kd], kf, s[nt]);
      }
    }
    if (t >= 66){                    // causal mask: cols >= 4224 (split 1 only)
      #pragma unroll
      for (int nt=0;nt<4;++nt){
        int jj = t*64 + nt*16 + lr - 4224;
        #pragma unroll
        for (int r=0;r<4;++r)
          if (jj > q_glob + r) s[nt][r] = -1e30f;
      }
    }
    #pragma unroll
    for (int nt=0;nt<4;++nt){
      #pragma unroll
      for (int r=0;r<4;++r){
        float p = exp2f(s[nt][r]);   // Q pre-scaled by log2e/sqrt(D)
        l_part[r] += p;
        int pc = nt*16 + lr;
        Ps[(w*16 + quad*4 + r)*64 + ((((pc>>3) ^ (quad<<1))<<3)) + (pc&7)] = f2bf(p);
      }
    }
    #pragma unroll
    for (int ks=0;ks<2;++ks){
      bf16x8 a = *(const bf16x8*)&Ps[(w*16+lr)*64 + ((((ks*4+quad) ^ (((lr>>2)&3)<<1)))<<3)];
      #pragma unroll
      for (int dt=0;dt<8;++dt){
        bf16x8 vf = *(const bf16x8*)&Vs[cur][(dt*16+lr)*64 + (((ks*4+quad)^(lr&7))*8)];
        o_acc[dt] = MFMA16(a, vf, o_acc[dt]);
      }
    }
    __syncthreads();                 // buffer rotation + DMA drain (one per tile)
  }
  #pragma unroll
  for (int r=0;r<4;++r){
    #pragma unroll
    for (int off=1; off<16; off<<=1)
      l_part[r] += __shfl_xor(l_part[r], off, 64);
  }
  int prow = (b*32+h)*128 + qt*64 + w*16 + quad*4;
  float* pob = po + (size_t)split*16384*128;
  #pragma unroll
  for (int dt=0;dt<8;++dt)
    #pragma unroll
    for (int r=0;r<4;++r)
      pob[(size_t)(prow + r)*128 + dt*16 + lr] = o_acc[dt][r];
  if (lr == 0){
    #pragma unroll
    for (int r=0;r<4;++r) lp[split*16384 + prow + r] = l_part[r];
  }
}

// ---------------- 7b) combine split-KV partials -> attn bf16 -----------------
__global__ void k_att_comb(const float* __restrict__ po, const float* __restrict__ lp,
                           short* __restrict__ attn)
{
  int i = blockIdx.x*256 + threadIdx.x;   // 524288 threads, 4 floats each
  int row = i >> 5, cp = (i & 31) * 4;    // row = (b*32+h)*128 + q
  float4 a = *(const float4*)(po + (size_t)row*128 + cp);
  float4 c = *(const float4*)(po + (size_t)(16384 + row)*128 + cp);
  float inv = 1.0f / (lp[row] + lp[16384 + row]);
  int bb = row >> 12, hh = (row >> 7) & 31, q = row & 127;
  short4 o;
  o.x = f2bf((a.x + c.x) * inv);
  o.y = f2bf((a.y + c.y) * inv);
  o.z = f2bf((a.z + c.z) * inv);
  o.w = f2bf((a.w + c.w) * inv);
  *(short4*)(attn + (size_t)(bb*128 + q)*4096 + hh*128 + cp) = o;
}

// -----------------------------------------------------------------------------
extern "C" void kernel_launch(void* const* d_in, const int* in_sizes, int n_in,
                              void* d_out, int out_size, void* d_ws, size_t ws_size,
                              hipStream_t stream)
{
  const float* hs  = (const float*)d_in[0];
  const float* q_w = (const float*)d_in[1];
  const float* q_b = (const float*)d_in[2];
  const float* k_w = (const float*)d_in[3];
  const float* k_b = (const float*)d_in[4];
  const float* v_w = (const float*)d_in[5];
  const float* v_b = (const float*)d_in[6];
  const float* o_w = (const float*)d_in[7];
  const int*   kq  = (const int*)d_in[8];
  const float* ksc = (const float*)d_in[9];
  const float* kmn = (const float*)d_in[10];
  const float* kf  = (const float*)d_in[11];
  const int*   vq  = (const int*)d_in[12];
  const float* vsc = (const float*)d_in[13];
  const float* vmn = (const float*)d_in[14];
  const float* vf  = (const float*)d_in[15];

  char* w = (char*)d_ws;
  short* hs_b = (short*)w;  w += (size_t)512*4096*2;        //  4.0 MB
  float* qkv  = (float*)w;  w += (size_t)512*6144*4;        // 12.6 MB
  short* Qb   = (short*)w;  w += (size_t)4*32*128*128*2;    //  4.2 MB
  short* Kb   = (short*)w;  w += (size_t)4*8*4352*128*2;    // 35.7 MB
  short* Vt   = (short*)w;  w += (size_t)4*8*4352*128*2;    // 35.7 MB
  short* attn = (short*)w;  w += (size_t)512*4096*2;        //  4.2 MB
  short* qwb  = (short*)w;  w += (size_t)4096*4096*2;       // 33.6 MB
  short* kwb  = (short*)w;  w += (size_t)1024*4096*2;       //  8.4 MB
  short* vwb  = (short*)w;  w += (size_t)1024*4096*2;       //  8.4 MB
  short* owb  = (short*)w;  w += (size_t)4096*4096*2;       // 33.6 MB (total ~180 MB)

  // split-K partials for gemm<0> alias Kb+Vt (71.3 MB >= 50.3 MB), dead before
  // k_rope/k_deq_* rewrite that region. attn split-KV partials alias qwb
  // (dead after gemm<0>); gemm<1> partials reuse qwb again (exact 33.55 MB).
  float* P0 = (float*)Kb;
  float* po = (float*)qwb;                                  // 2*16384*128*4 = 16.78 MB
  float* lp = (float*)((char*)qwb + (size_t)2*16384*128*4); // 2*16384*4    = 128 KB
  float* P1 = (float*)qwb;

  k_cast_hs <<<2048, 256, 0, stream>>>(hs, hs_b);
  k_conv_w  <<<2560, 256, 0, stream>>>(q_w, k_w, v_w, o_w, qwb, kwb, vwb, owb);
  k_gemm<0> <<<768,  256, 0, stream>>>(hs_b, qwb, kwb, vwb, P0);
  k_comb<0> <<<3072, 256, 0, stream>>>(P0, q_b, k_b, v_b, qkv);
  k_rope    <<<192,  256, 0, stream>>>(qkv, kf, Qb, Kb);
  k_vtrans  <<<64,   256, 0, stream>>>(qkv, vf, Vt);
  k_deq_k   <<<2048, 256, 0, stream>>>(kq, ksc, kmn, Kb);
  k_deq_v   <<<2048, 256, 0, stream>>>(vq, vsc, vmn, Vt);
  k_attn    <<<512,  256, 0, stream>>>(Qb, Kb, Vt, po, lp);
  k_att_comb<<<2048, 256, 0, stream>>>(po, lp, attn);
  k_gemm<1> <<<512,  256, 0, stream>>>(attn, owb, nullptr, nullptr, P1);
  k_comb<1> <<<2048, 256, 0, stream>>>(P1, nullptr, nullptr, nullptr, (float*)d_out);
}

// Round 4
// 450.808 us; speedup vs baseline: 1.3400x; 1.0015x over previous
//
#include <hip/hip_runtime.h>
#include <hip/hip_bf16.h>
#include <math.h>

using bf16x8 = __attribute__((ext_vector_type(8))) short;
using f32x4  = __attribute__((ext_vector_type(4))) float;

#define MFMA16(a,b,c) __builtin_amdgcn_mfma_f32_16x16x32_bf16((a),(b),(c),0,0,0)

__device__ __forceinline__ short f2bf(float f){
  union { __hip_bfloat16 h; short s; } u;
  u.h = __float2bfloat16(f);
  return u.s;
}

// async global->LDS, 16B per lane. LDS dest = wave-uniform base + lane*16.
__device__ __forceinline__ void gl_lds16(const void* g, void* l){
  __builtin_amdgcn_global_load_lds(
      (const __attribute__((address_space(1))) unsigned int*)g,
      (__attribute__((address_space(3))) unsigned int*)l, 16, 0, 0);
}

// Problem constants: b=4, q_len=128, H=4096, NH=32, KVH=8, D=128,
// n_qk=n_qv=4096, res=128, past=4224, kv_seq=4352 (= 68 tiles of 64)

// ---------------- 1) cast hidden_states fp32 -> bf16 (512x4096) --------------
__global__ void k_cast_hs(const float* __restrict__ src, short* __restrict__ dst){
  int i = blockIdx.x*256 + threadIdx.x;
  float4 v = reinterpret_cast<const float4*>(src)[i];
  short4 o;
  o.x = f2bf(v.x); o.y = f2bf(v.y); o.z = f2bf(v.z); o.w = f2bf(v.w);
  reinterpret_cast<short4*>(dst)[i] = o;
}

// ---------------- 2/8) MFMA GEMM: C = A(bf16) @ B(fp32)^T, split-K=4 ---------
// 128x128 tile, BK=64, 256 threads (4 waves of 64x64), double-buffered LDS,
// 2 blocks/CU. A (bf16) staged via global_load_lds; B (fp32 weights) is
// reg-staged: global float4 loads issued BEFORE the MFMA block (HBM latency
// hides under compute), converted to bf16 and ds_written after compute.
// This fuses the old k_conv_w weight-conversion pass into the GEMM (saves a
// 252 MB HBM round-trip); results are bitwise identical (same f2bf rounding,
// same physical-chunk = logical^(row&7) LDS layout the gl_lds swizzle gave).
// Split-K=4 (1024 K each); fp32 partials summed (+bias) by k_comb.
template<int MODE>
__global__ __launch_bounds__(256,2) void k_gemm(
    const short* __restrict__ A,
    const float* __restrict__ B0, const float* __restrict__ B1, const float* __restrict__ B2,
    float* __restrict__ P)
{
  constexpr int K = 4096;
  constexpr int NST = (MODE == 0) ? 6144 : 4096;
  constexpr int NTX = (MODE == 0) ? 6 : 4;      // n-tiles per XCD
  int bid = blockIdx.x;
  int xc = bid & 7, idx = bid >> 3;
  int m_tile = idx & 3, split = (idx >> 2) & 3, nl = idx >> 4;
  int n_tile = xc*NTX + nl;
  int mb = m_tile*128, nb = n_tile*128;
  const float* Bsrc = B0; int nrel = nb;
  if (MODE == 0){
    if (nb >= 5120){ Bsrc = B2; nrel = nb - 5120; }
    else if (nb >= 4096){ Bsrc = B1; nrel = nb - 4096; }
  }
  __shared__ short As[2][128*64];   // 16 KB each
  __shared__ short Bs[2][128*64];   // 16 KB each
  int tid = threadIdx.x, w = tid>>6, L = tid&63;
  int lr = L&15, quad = L>>4;
  int wm = (w>>1)*64, wn = (w&1)*64;
  f32x4 acc[4][4] = {};
  int kb0 = split*1024;

  auto stageA = [&](int buf, int kb){
    #pragma unroll
    for (int i=0;i<4;++i){
      int row = w*32 + i*8 + (L>>3);
      int cl = (L&7) ^ (row&7);
      gl_lds16(A + (size_t)(mb+row)*K + kb + cl*8, &As[buf][(w*32+i*8)*64]);
    }
  };
  // reg-stage B: 4 chunks of 8 fp32 per thread (1024 chunks = 128 rows x 8)
  auto loadB = [&](int kb, float4* breg){
    #pragma unroll
    for (int i=0;i<4;++i){
      int cid = i*256 + tid;
      int row = cid >> 3, c = cid & 7;
      const float* src = Bsrc + (size_t)(nrel+row)*K + kb + c*8;
      breg[i*2]   = *(const float4*)(src);
      breg[i*2+1] = *(const float4*)(src+4);
    }
  };
  auto writeB = [&](int buf, const float4* breg){
    #pragma unroll
    for (int i=0;i<4;++i){
      int cid = i*256 + tid;
      int row = cid >> 3, c = cid & 7;
      const float* f = (const float*)&breg[i*2];
      bf16x8 o;
      #pragma unroll
      for (int e=0;e<8;++e) o[e] = f2bf(f[e]);
      *(bf16x8*)&Bs[buf][row*64 + ((c ^ (row&7))<<3)] = o;
    }
  };
  auto compute = [&](int buf){
    #pragma unroll
    for (int kd=0;kd<2;++kd){
      bf16x8 af[4], bfr[4];
      #pragma unroll
      for (int i=0;i<4;++i)
        af[i] = *(const bf16x8*)&As[buf][(wm+i*16+lr)*64 + (((kd*4+quad)^(lr&7))*8)];
      #pragma unroll
      for (int j=0;j<4;++j)
        bfr[j] = *(const bf16x8*)&Bs[buf][(wn+j*16+lr)*64 + (((kd*4+quad)^(lr&7))*8)];
      #pragma unroll
      for (int i=0;i<4;++i)
        #pragma unroll
        for (int j=0;j<4;++j)
          acc[i][j] = MFMA16(af[i], bfr[j], acc[i][j]);
    }
  };

  float4 breg[8];
  loadB(kb0, breg);
  stageA(0, kb0);
  writeB(0, breg);
  __syncthreads();
  for (int s=0; s<16; ++s){
    int cur = s & 1;
    if (s < 15){
      stageA(cur^1, kb0 + (s+1)*64);
      loadB(kb0 + (s+1)*64, breg);   // in flight across compute
    }
    compute(cur);
    if (s < 15) writeB(cur^1, breg); // vmcnt wait lands here, after MFMAs
    __syncthreads();
  }
  #pragma unroll
  for (int mf=0;mf<4;++mf){
    #pragma unroll
    for (int nf=0;nf<4;++nf){
      int col = nb + wn + nf*16 + lr;
      #pragma unroll
      for (int r=0;r<4;++r){
        int row = mb + wm + mf*16 + quad*4 + r;   // C/D: row = quad*4+reg, col = lane&15
        P[((size_t)(split*512 + row))*NST + col] = acc[mf][nf][r];
      }
    }
  }
}

// ---------------- 2b/8b) combine split-K partials (+bias for MODE 0) ---------
template<int MODE>
__global__ void k_comb(const float* __restrict__ P, const float* __restrict__ qb,
                       const float* __restrict__ kb, const float* __restrict__ vb,
                       float* __restrict__ O)
{
  constexpr int NST = (MODE == 0) ? 6144 : 4096;
  constexpr int NC  = NST/4;
  int i = blockIdx.x*256 + threadIdx.x;
  int row = i / NC, cp = (i % NC)*4;
  size_t off = (size_t)row*NST + cp;
  constexpr size_t SS = (size_t)512*NST;
  float4 a = *(const float4*)(P + off);
  float4 b2 = *(const float4*)(P + off + SS);
  float4 c = *(const float4*)(P + off + 2*SS);
  float4 d = *(const float4*)(P + off + 3*SS);
  float4 s;
  s.x = a.x+b2.x+c.x+d.x; s.y = a.y+b2.y+c.y+d.y;
  s.z = a.z+b2.z+c.z+d.z; s.w = a.w+b2.w+c.w+d.w;
  if (MODE == 0){
    const float* bs; int bc;
    if (cp < 4096){ bs = qb; bc = cp; }
    else if (cp < 5120){ bs = kb; bc = cp - 4096; }
    else { bs = vb; bc = cp - 5120; }
    float4 bv = *(const float4*)(bs + bc);
    s.x += bv.x; s.y += bv.y; s.z += bv.z; s.w += bv.w;
  }
  *(float4*)(O + off) = s;
}

// ---------------- 3) RoPE for Q and K_new, + key_full_past cast --------------
__global__ void k_rope(const float* __restrict__ qkv, const float* __restrict__ kfull,
                       short* __restrict__ Qb, short* __restrict__ Kb)
{
  int bid = blockIdx.x, tid = threadIdx.x;
  const float LOG2_1E6_DIV64 = 0.3114307588956902f;  // log2(1e6)/64
  if (bid < 128){                                     // Q: (b,h) per WG
    int b = bid >> 5, h = bid & 31;
    for (int i=0;i<64;++i){
      int e = i*256 + tid, q = e>>7, d = e&127, fi = d&63;
      float inv = exp2f(-LOG2_1E6_DIV64 * (float)fi);
      float ang = (float)(4224 + q) * inv;
      float sn, cs; sincosf(ang, &sn, &cs);
      const float* row = qkv + (b*128+q)*6144 + h*128;
      float x = row[d], p = row[d^64];
      float o = (d < 64) ? (x*cs - p*sn) : (x*cs + p*sn);
      Qb[((b*32+h)*128 + q)*128 + d] = f2bf(o * 0.12751743f); // log2e/sqrt(128)
    }
  } else if (bid < 160){                              // K_new: (b,kvh) per WG
    int g = bid - 128;                                // g = b*8+kvh
    for (int i=0;i<64;++i){
      int e = i*256 + tid, q = e>>7, d = e&127, fi = d&63;
      float inv = exp2f(-LOG2_1E6_DIV64 * (float)fi);
      float ang = (float)(4224 + q) * inv;
      float sn, cs; sincosf(ang, &sn, &cs);
      const float* row = qkv + ((g>>3)*128+q)*6144 + 4096 + (g&7)*128;
      float x = row[d], p = row[d^64];
      float o = (d < 64) ? (x*cs - p*sn) : (x*cs + p*sn);
      Kb[(g*4352 + 4224 + q)*128 + d] = f2bf(o);
    }
  } else {                                            // key_full_past cast copy
    int g = bid - 160;
    for (int i=0;i<64;++i){
      int e = i*256 + tid, r = e>>7, d = e&127;
      Kb[(g*4352 + 4096 + r)*128 + d] = f2bf(kfull[(g*128 + r)*128 + d]);
    }
  }
}

// ---------------- 4) V transpose: value_full_past & V_new -> Vt[d][n] --------
__global__ void k_vtrans(const float* __restrict__ qkv, const float* __restrict__ vfull,
                         short* __restrict__ Vt)
{
  __shared__ float T[128][132];
  int bid = blockIdx.x;                 // 64 = 32 groups x 2 sources
  int srcsel = bid & 1, g = bid >> 1;   // g = b*8+kvh
  int tid = threadIdx.x;
  for (int i=0;i<64;++i){
    int e = i*256 + tid, r = e>>7, dd = e&127;
    float v;
    if (srcsel == 0) v = vfull[(g*128 + r)*128 + dd];
    else             v = qkv[((g>>3)*128 + r)*6144 + 5120 + (g&7)*128 + dd];
    T[r][dd] = v;
  }
  __syncthreads();
  int n0 = (srcsel == 0) ? 4096 : 4224;
  for (int i=0;i<64;++i){
    int e = i*256 + tid, dd = e>>7, q = e&127;
    Vt[(g*128 + dd)*4352 + n0 + q] = f2bf(T[q][dd]);
  }
}

// ---------------- 5) dequant 2-bit keys -> Kb[n][d] (n<4096) -----------------
__global__ void k_deq_k(const int* __restrict__ kq, const float* __restrict__ ksc,
                        const float* __restrict__ kmn, short* __restrict__ Kb)
{
  __shared__ short KT[64][136];
  int bid = blockIdx.x;                  // 2048 = 32 groups x 64 n-tiles
  int nt = bid & 63, g = bid >> 6;
  int tid = threadIdx.x;
  int d = tid >> 1, half = tid & 1;
  float sc = ksc[(g*128 + d)*64 + nt];
  float mn = kmn[(g*128 + d)*64 + nt];
  #pragma unroll
  for (int j=0;j<2;++j){
    unsigned w = (unsigned)kq[(g*128 + d)*256 + nt*4 + half*2 + j];
    int nbase = (half*2 + j)*16;
    #pragma unroll
    for (int e=0;e<16;++e){
      float v = (float)((w >> (2*e)) & 3u) * sc + mn;
      KT[nbase + e][d] = f2bf(v);
    }
  }
  __syncthreads();
  int n = tid >> 2, c = (tid & 3) * 32;
  const int4* s4 = (const int4*)&KT[n][c];
  int4* d4 = (int4*)(Kb + (g*4352 + nt*64 + n)*128 + c);
  d4[0]=s4[0]; d4[1]=s4[1]; d4[2]=s4[2]; d4[3]=s4[3];
}

// ---------------- 6) dequant 2-bit values -> Vt[d][n] (n<4096) ---------------
__global__ void k_deq_v(const int* __restrict__ vq, const float* __restrict__ vsc,
                        const float* __restrict__ vmn, short* __restrict__ Vt)
{
  __shared__ short VT[128][72];
  int bid = blockIdx.x;                  // 2048
  int nt = bid & 63, g = bid >> 6;
  int tid = threadIdx.x;
  int n = tid >> 2, dp = tid & 3;
  int nglob = nt*64 + n;
  #pragma unroll
  for (int j=0;j<2;++j){
    int dw = dp*2 + j;
    float sc = vsc[(g*4096 + nglob)*2 + (dw>>2)];
    float mn = vmn[(g*4096 + nglob)*2 + (dw>>2)];
    unsigned w = (unsigned)vq[(g*4096 + nglob)*8 + dw];
    #pragma unroll
    for (int e=0;e<16;++e){
      float v = (float)((w >> (2*e)) & 3u) * sc + mn;
      VT[dw*16 + e][n] = f2bf(v);
    }
  }
  __syncthreads();
  int d = tid >> 1, c = (tid & 1) * 32;
  const int4* s4 = (const int4*)&VT[d][c];
  int4* d4 = (int4*)(Vt + (g*128 + d)*4352 + nt*64 + c);
  d4[0]=s4[0]; d4[1]=s4[1]; d4[2]=s4[2]; d4[3]=s4[3];
}

// ---------------- 7) fused flash attention, split-KV (2 blocks/CU) -----------
__global__ __launch_bounds__(256,2) void k_attn(
    const short* __restrict__ Qb, const short* __restrict__ Kb,
    const short* __restrict__ Vt, float* __restrict__ po, float* __restrict__ lp)
{
  __shared__ short Ks[2][64*128];    // 2 x 16 KB
  __shared__ short Vs[2][128*64];    // 2 x 16 KB
  __shared__ short Ps[64*64];        // 8 KB, chunk-XOR swizzled
  int bid = blockIdx.x;              // 512 = kvh(8) x [split(2) x m(8) x b(4)]
  int kvh = bid & 7, y = bid >> 3;
  int split = y & 1, m = (y >> 1) & 7, b = y >> 4;
  int qt = m & 1, hloc = m >> 1;
  int h = kvh*4 + hloc;
  int g = b*8 + kvh;
  int tid = threadIdx.x, w = tid>>6, L = tid&63;
  int lr = L&15, quad = L>>4;
  const short* kbase = Kb + (size_t)g*4352*128;
  const short* vbase = Vt + (size_t)g*128*4352;

  // Q fragments straight from global (each element read exactly once)
  bf16x8 qf[4];
  {
    const short* qrow = Qb + ((size_t)(b*32+h)*128 + qt*64 + w*16 + lr)*128;
    #pragma unroll
    for (int kd=0;kd<4;++kd)
      qf[kd] = *(const bf16x8*)(qrow + (kd*4+quad)*8);
  }

  auto stageKV = [&](int t, int buf){
    #pragma unroll
    for (int i=0;i<4;++i){
      int row = w*16 + i*4 + (L>>4);
      int cl = (L&15) ^ (row&7);
      gl_lds16(kbase + (size_t)(t*64+row)*128 + cl*8, &Ks[buf][(w*16+i*4)*128]);
    }
    #pragma unroll
    for (int i=0;i<4;++i){
      int row = w*32 + i*8 + (L>>3);
      int cl = (L&7) ^ (row&7);
      gl_lds16(vbase + (size_t)row*4352 + t*64 + cl*8, &Vs[buf][(w*32+i*8)*64]);
    }
  };

  int t0 = split*34;
  stageKV(t0, 0);
  __syncthreads();

  float l_part[4] = {0.f,0.f,0.f,0.f};
  f32x4 o_acc[8] = {};
  int q_glob = qt*64 + w*16 + quad*4;

  for (int ti=0; ti<34; ++ti){
    int t = t0 + ti;
    int cur = ti & 1;
    if (ti < 33) stageKV(t+1, cur^1);
    f32x4 s[4] = {};
    #pragma unroll
    for (int kd=0;kd<4;++kd){
      #pragma unroll
      for (int nt=0;nt<4;++nt){
        bf16x8 kf = *(const bf16x8*)&Ks[cur][(nt*16+lr)*128 + (((kd*4+quad)^(lr&7))*8)];
        s[nt] = MFMA16(qf[kd], kf, s[nt]);
      }
    }
    if (t >= 66){                    // causal mask: cols >= 4224 (split 1 only)
      #pragma unroll
      for (int nt=0;nt<4;++nt){
        int jj = t*64 + nt*16 + lr - 4224;
        #pragma unroll
        for (int r=0;r<4;++r)
          if (jj > q_glob + r) s[nt][r] = -1e30f;
      }
    }
    #pragma unroll
    for (int nt=0;nt<4;++nt){
      #pragma unroll
      for (int r=0;r<4;++r){
        float p = exp2f(s[nt][r]);   // Q pre-scaled by log2e/sqrt(D)
        l_part[r] += p;
        int pc = nt*16 + lr;
        Ps[(w*16 + quad*4 + r)*64 + ((((pc>>3) ^ (quad<<1))<<3)) + (pc&7)] = f2bf(p);
      }
    }
    #pragma unroll
    for (int ks=0;ks<2;++ks){
      bf16x8 a = *(const bf16x8*)&Ps[(w*16+lr)*64 + ((((ks*4+quad) ^ (((lr>>2)&3)<<1)))<<3)];
      #pragma unroll
      for (int dt=0;dt<8;++dt){
        bf16x8 vf = *(const bf16x8*)&Vs[cur][(dt*16+lr)*64 + (((ks*4+quad)^(lr&7))*8)];
        o_acc[dt] = MFMA16(a, vf, o_acc[dt]);
      }
    }
    __syncthreads();                 // buffer rotation + DMA drain (one per tile)
  }
  #pragma unroll
  for (int r=0;r<4;++r){
    #pragma unroll
    for (int off=1; off<16; off<<=1)
      l_part[r] += __shfl_xor(l_part[r], off, 64);
  }
  int prow = (b*32+h)*128 + qt*64 + w*16 + quad*4;
  float* pob = po + (size_t)split*16384*128;
  #pragma unroll
  for (int dt=0;dt<8;++dt)
    #pragma unroll
    for (int r=0;r<4;++r)
      pob[(size_t)(prow + r)*128 + dt*16 + lr] = o_acc[dt][r];
  if (lr == 0){
    #pragma unroll
    for (int r=0;r<4;++r) lp[split*16384 + prow + r] = l_part[r];
  }
}

// ---------------- 7b) combine split-KV partials -> attn bf16 -----------------
__global__ void k_att_comb(const float* __restrict__ po, const float* __restrict__ lp,
                           short* __restrict__ attn)
{
  int i = blockIdx.x*256 + threadIdx.x;   // 524288 threads, 4 floats each
  int row = i >> 5, cp = (i & 31) * 4;    // row = (b*32+h)*128 + q
  float4 a = *(const float4*)(po + (size_t)row*128 + cp);
  float4 c = *(const float4*)(po + (size_t)(16384 + row)*128 + cp);
  float inv = 1.0f / (lp[row] + lp[16384 + row]);
  int bb = row >> 12, hh = (row >> 7) & 31, q = row & 127;
  short4 o;
  o.x = f2bf((a.x + c.x) * inv);
  o.y = f2bf((a.y + c.y) * inv);
  o.z = f2bf((a.z + c.z) * inv);
  o.w = f2bf((a.w + c.w) * inv);
  *(short4*)(attn + (size_t)(bb*128 + q)*4096 + hh*128 + cp) = o;
}

// -----------------------------------------------------------------------------
extern "C" void kernel_launch(void* const* d_in, const int* in_sizes, int n_in,
                              void* d_out, int out_size, void* d_ws, size_t ws_size,
                              hipStream_t stream)
{
  const float* hs  = (const float*)d_in[0];
  const float* q_w = (const float*)d_in[1];
  const float* q_b = (const float*)d_in[2];
  const float* k_w = (const float*)d_in[3];
  const float* k_b = (const float*)d_in[4];
  const float* v_w = (const float*)d_in[5];
  const float* v_b = (const float*)d_in[6];
  const float* o_w = (const float*)d_in[7];
  const int*   kq  = (const int*)d_in[8];
  const float* ksc = (const float*)d_in[9];
  const float* kmn = (const float*)d_in[10];
  const float* kf  = (const float*)d_in[11];
  const int*   vq  = (const int*)d_in[12];
  const float* vsc = (const float*)d_in[13];
  const float* vmn = (const float*)d_in[14];
  const float* vf  = (const float*)d_in[15];

  char* w = (char*)d_ws;
  short* hs_b = (short*)w;  w += (size_t)512*4096*2;        //  4.0 MB
  float* qkv  = (float*)w;  w += (size_t)512*6144*4;        // 12.6 MB
  short* Qb   = (short*)w;  w += (size_t)4*32*128*128*2;    //  4.2 MB
  short* Kb   = (short*)w;  w += (size_t)4*8*4352*128*2;    // 35.7 MB
  short* Vt   = (short*)w;  w += (size_t)4*8*4352*128*2;    // 35.7 MB
  short* attn = (short*)w;  w += (size_t)512*4096*2;        //  4.2 MB
  float* scratch = (float*)w;                               // remaining ~84 MB

  // split-K partials for gemm<0> alias Kb+Vt (71.3 MB >= 50.3 MB), dead before
  // k_rope/k_deq_* rewrite that region. attn split-KV partials and gemm<1>
  // partials live in the scratch region (weights now consumed fp32 in-GEMM).
  float* P0 = (float*)Kb;
  float* po = scratch;                                      // 2*16384*128*4 = 16.78 MB
  float* lp = scratch + (size_t)2*16384*128;                // 2*16384*4    = 128 KB
  float* P1 = scratch;                                      // reused after att_comb

  k_cast_hs <<<2048, 256, 0, stream>>>(hs, hs_b);
  k_gemm<0> <<<768,  256, 0, stream>>>(hs_b, q_w, k_w, v_w, P0);
  k_comb<0> <<<3072, 256, 0, stream>>>(P0, q_b, k_b, v_b, qkv);
  k_rope    <<<192,  256, 0, stream>>>(qkv, kf, Qb, Kb);
  k_vtrans  <<<64,   256, 0, stream>>>(qkv, vf, Vt);
  k_deq_k   <<<2048, 256, 0, stream>>>(kq, ksc, kmn, Kb);
  k_deq_v   <<<2048, 256, 0, stream>>>(vq, vsc, vmn, Vt);
  k_attn    <<<512,  256, 0, stream>>>(Qb, Kb, Vt, po, lp);
  k_att_comb<<<2048, 256, 0, stream>>>(po, lp, attn);
  k_gemm<1> <<<512,  256, 0, stream>>>(attn, o_w, nullptr, nullptr, P1);
  k_comb<1> <<<2048, 256, 0, stream>>>(P1, nullptr, nullptr, nullptr, (float*)d_out);
}

// Round 5
// 440.725 us; speedup vs baseline: 1.3706x; 1.0229x over previous
//
#include <hip/hip_runtime.h>
#include <hip/hip_bf16.h>
#include <math.h>

using bf16x8 = __attribute__((ext_vector_type(8))) short;
using f32x4  = __attribute__((ext_vector_type(4))) float;

#define MFMA16(a,b,c) __builtin_amdgcn_mfma_f32_16x16x32_bf16((a),(b),(c),0,0,0)

__device__ __forceinline__ short f2bf(float f){
  union { __hip_bfloat16 h; short s; } u;
  u.h = __float2bfloat16(f);
  return u.s;
}

// async global->LDS, 16B per lane. LDS dest = wave-uniform base + lane*16.
__device__ __forceinline__ void gl_lds16(const void* g, void* l){
  __builtin_amdgcn_global_load_lds(
      (const __attribute__((address_space(1))) unsigned int*)g,
      (__attribute__((address_space(3))) unsigned int*)l, 16, 0, 0);
}

// Problem constants: b=4, q_len=128, H=4096, NH=32, KVH=8, D=128,
// n_qk=n_qv=4096, res=128, past=4224, kv_seq=4352 (= 68 tiles of 64)

// ---------------- 1) cast hidden_states fp32 -> bf16 (512x4096) --------------
__global__ void k_cast_hs(const float* __restrict__ src, short* __restrict__ dst){
  int i = blockIdx.x*256 + threadIdx.x;
  float4 v = reinterpret_cast<const float4*>(src)[i];
  short4 o;
  o.x = f2bf(v.x); o.y = f2bf(v.y); o.z = f2bf(v.z); o.w = f2bf(v.w);
  reinterpret_cast<short4*>(dst)[i] = o;
}

// ---------------- 2/8) MFMA GEMM: C = A(bf16) @ B(fp32)^T ---------------------
// 128x128 tile, BK=64, 256 threads (4 waves of 64x64), double-buffered LDS,
// 2 blocks/CU. A (bf16) via global_load_lds 1-step ahead; B (fp32 weights)
// reg-staged 2 STEPS ahead in two statically-named reg sets (bregE/bregO):
// loadB(s+2) issues at top of step s, drains at step-s barrier, so the
// writeB(s+1) in step s+1 never waits on VMEM. Converts fp32->bf16 inline
// (no separate weight-conversion pass; rounding identical to R2).
// Grids: MODE0 split-K=2 -> 384 blocks (single resident round at 2/CU),
// MODE1 split-K=4 -> 512 blocks (exactly 2/CU). Partials summed by k_comb.
template<int MODE>
__global__ __launch_bounds__(256,2) void k_gemm(
    const short* __restrict__ A,
    const float* __restrict__ B0, const float* __restrict__ B1, const float* __restrict__ B2,
    float* __restrict__ P)
{
  constexpr int K = 4096;
  constexpr int NST = (MODE == 0) ? 6144 : 4096;
  constexpr int NTX = (MODE == 0) ? 6 : 4;      // n-tiles per XCD
  constexpr int SPLITS = (MODE == 0) ? 2 : 4;
  constexpr int SB     = (MODE == 0) ? 1 : 2;   // log2(SPLITS)
  constexpr int NSTEPS = K / SPLITS / 64;       // 32 / 16 (even)
  int bid = blockIdx.x;
  int xc = bid & 7, idx = bid >> 3;
  int m_tile = idx & 3, split = (idx >> 2) & (SPLITS-1), nl = idx >> (2+SB);
  int n_tile = xc*NTX + nl;
  int mb = m_tile*128, nb = n_tile*128;
  const float* Bsrc = B0; int nrel = nb;
  if (MODE == 0){
    if (nb >= 5120){ Bsrc = B2; nrel = nb - 5120; }
    else if (nb >= 4096){ Bsrc = B1; nrel = nb - 4096; }
  }
  __shared__ short As[2][128*64];   // 16 KB each
  __shared__ short Bs[2][128*64];   // 16 KB each
  int tid = threadIdx.x, w = tid>>6, L = tid&63;
  int lr = L&15, quad = L>>4;
  int wm = (w>>1)*64, wn = (w&1)*64;
  f32x4 acc[4][4] = {};
  int kb0 = split * (K/SPLITS);

  auto stageA = [&](int buf, int kb){
    #pragma unroll
    for (int i=0;i<4;++i){
      int row = w*32 + i*8 + (L>>3);
      int cl = (L&7) ^ (row&7);
      gl_lds16(A + (size_t)(mb+row)*K + kb + cl*8, &As[buf][(w*32+i*8)*64]);
    }
  };
  // reg-stage B: 4 chunks of 8 fp32 per thread (1024 chunks = 128 rows x 8)
  auto loadB = [&](int kb, float4* breg){
    #pragma unroll
    for (int i=0;i<4;++i){
      int cid = i*256 + tid;
      int row = cid >> 3, c = cid & 7;
      const float* src = Bsrc + (size_t)(nrel+row)*K + kb + c*8;
      breg[i*2]   = *(const float4*)(src);
      breg[i*2+1] = *(const float4*)(src+4);
    }
  };
  auto writeB = [&](int buf, const float4* breg){
    #pragma unroll
    for (int i=0;i<4;++i){
      int cid = i*256 + tid;
      int row = cid >> 3, c = cid & 7;
      const float* f = (const float*)&breg[i*2];
      bf16x8 o;
      #pragma unroll
      for (int e=0;e<8;++e) o[e] = f2bf(f[e]);
      *(bf16x8*)&Bs[buf][row*64 + ((c ^ (row&7))<<3)] = o;
    }
  };
  auto compute = [&](int buf){
    #pragma unroll
    for (int kd=0;kd<2;++kd){
      bf16x8 af[4], bfr[4];
      #pragma unroll
      for (int i=0;i<4;++i)
        af[i] = *(const bf16x8*)&As[buf][(wm+i*16+lr)*64 + (((kd*4+quad)^(lr&7))*8)];
      #pragma unroll
      for (int j=0;j<4;++j)
        bfr[j] = *(const bf16x8*)&Bs[buf][(wn+j*16+lr)*64 + (((kd*4+quad)^(lr&7))*8)];
      #pragma unroll
      for (int i=0;i<4;++i)
        #pragma unroll
        for (int j=0;j<4;++j)
          acc[i][j] = MFMA16(af[i], bfr[j], acc[i][j]);
    }
  };

  float4 bregE[8], bregO[8];        // static names only (rule #20)
  stageA(0, kb0);                   // DMA overlaps the prologue B latency
  loadB(kb0, bregE);
  writeB(0, bregE);                 // one-time exposed wait (~HBM latency)
  loadB(kb0 + 64, bregO);
  __syncthreads();                  // drains stageA(0) + loadB(1)

  for (int su=0; su<NSTEPS/2; ++su){
    {                               // even step s = 2*su, cur = 0
      int s = su*2;
      if (s+1 < NSTEPS) stageA(1, kb0 + (s+1)*64);
      if (s+2 < NSTEPS) loadB(kb0 + (s+2)*64, bregE);
      if (s+1 < NSTEPS) writeB(1, bregO);   // data drained at prev barrier
      compute(0);
      __syncthreads();
    }
    {                               // odd step s = 2*su+1, cur = 1
      int s = su*2+1;
      if (s+1 < NSTEPS) stageA(0, kb0 + (s+1)*64);
      if (s+2 < NSTEPS) loadB(kb0 + (s+2)*64, bregO);
      if (s+1 < NSTEPS) writeB(0, bregE);
      compute(1);
      __syncthreads();
    }
  }
  #pragma unroll
  for (int mf=0;mf<4;++mf){
    #pragma unroll
    for (int nf=0;nf<4;++nf){
      int col = nb + wn + nf*16 + lr;
      #pragma unroll
      for (int r=0;r<4;++r){
        int row = mb + wm + mf*16 + quad*4 + r;   // C/D: row = quad*4+reg, col = lane&15
        P[((size_t)(split*512 + row))*NST + col] = acc[mf][nf][r];
      }
    }
  }
}

// ---------------- 2b/8b) combine split-K partials (+bias for MODE 0) ---------
template<int MODE>
__global__ void k_comb(const float* __restrict__ P, const float* __restrict__ qb,
                       const float* __restrict__ kb, const float* __restrict__ vb,
                       float* __restrict__ O)
{
  constexpr int NST = (MODE == 0) ? 6144 : 4096;
  constexpr int NC  = NST/4;
  constexpr int SPL = (MODE == 0) ? 2 : 4;
  int i = blockIdx.x*256 + threadIdx.x;
  int row = i / NC, cp = (i % NC)*4;
  size_t off = (size_t)row*NST + cp;
  constexpr size_t SS = (size_t)512*NST;
  float4 s = *(const float4*)(P + off);
  #pragma unroll
  for (int k=1;k<SPL;++k){
    float4 t = *(const float4*)(P + off + (size_t)k*SS);
    s.x += t.x; s.y += t.y; s.z += t.z; s.w += t.w;
  }
  if (MODE == 0){
    const float* bs; int bc;
    if (cp < 4096){ bs = qb; bc = cp; }
    else if (cp < 5120){ bs = kb; bc = cp - 4096; }
    else { bs = vb; bc = cp - 5120; }
    float4 bv = *(const float4*)(bs + bc);
    s.x += bv.x; s.y += bv.y; s.z += bv.z; s.w += bv.w;
  }
  *(float4*)(O + off) = s;
}

// ---------------- 3) RoPE for Q and K_new, + key_full_past cast --------------
__global__ void k_rope(const float* __restrict__ qkv, const float* __restrict__ kfull,
                       short* __restrict__ Qb, short* __restrict__ Kb)
{
  int bid = blockIdx.x, tid = threadIdx.x;
  const float LOG2_1E6_DIV64 = 0.3114307588956902f;  // log2(1e6)/64
  if (bid < 128){                                     // Q: (b,h) per WG
    int b = bid >> 5, h = bid & 31;
    for (int i=0;i<64;++i){
      int e = i*256 + tid, q = e>>7, d = e&127, fi = d&63;
      float inv = exp2f(-LOG2_1E6_DIV64 * (float)fi);
      float ang = (float)(4224 + q) * inv;
      float sn, cs; sincosf(ang, &sn, &cs);
      const float* row = qkv + (b*128+q)*6144 + h*128;
      float x = row[d], p = row[d^64];
      float o = (d < 64) ? (x*cs - p*sn) : (x*cs + p*sn);
      Qb[((b*32+h)*128 + q)*128 + d] = f2bf(o * 0.12751743f); // log2e/sqrt(128)
    }
  } else if (bid < 160){                              // K_new: (b,kvh) per WG
    int g = bid - 128;                                // g = b*8+kvh
    for (int i=0;i<64;++i){
      int e = i*256 + tid, q = e>>7, d = e&127, fi = d&63;
      float inv = exp2f(-LOG2_1E6_DIV64 * (float)fi);
      float ang = (float)(4224 + q) * inv;
      float sn, cs; sincosf(ang, &sn, &cs);
      const float* row = qkv + ((g>>3)*128+q)*6144 + 4096 + (g&7)*128;
      float x = row[d], p = row[d^64];
      float o = (d < 64) ? (x*cs - p*sn) : (x*cs + p*sn);
      Kb[(g*4352 + 4224 + q)*128 + d] = f2bf(o);
    }
  } else {                                            // key_full_past cast copy
    int g = bid - 160;
    for (int i=0;i<64;++i){
      int e = i*256 + tid, r = e>>7, d = e&127;
      Kb[(g*4352 + 4096 + r)*128 + d] = f2bf(kfull[(g*128 + r)*128 + d]);
    }
  }
}

// ---------------- 4) V transpose: value_full_past & V_new -> Vt[d][n] --------
__global__ void k_vtrans(const float* __restrict__ qkv, const float* __restrict__ vfull,
                         short* __restrict__ Vt)
{
  __shared__ float T[128][132];
  int bid = blockIdx.x;                 // 64 = 32 groups x 2 sources
  int srcsel = bid & 1, g = bid >> 1;   // g = b*8+kvh
  int tid = threadIdx.x;
  for (int i=0;i<64;++i){
    int e = i*256 + tid, r = e>>7, dd = e&127;
    float v;
    if (srcsel == 0) v = vfull[(g*128 + r)*128 + dd];
    else             v = qkv[((g>>3)*128 + r)*6144 + 5120 + (g&7)*128 + dd];
    T[r][dd] = v;
  }
  __syncthreads();
  int n0 = (srcsel == 0) ? 4096 : 4224;
  for (int i=0;i<64;++i){
    int e = i*256 + tid, dd = e>>7, q = e&127;
    Vt[(g*128 + dd)*4352 + n0 + q] = f2bf(T[q][dd]);
  }
}

// ---------------- 5) dequant 2-bit keys -> Kb[n][d] (n<4096) -----------------
__global__ void k_deq_k(const int* __restrict__ kq, const float* __restrict__ ksc,
                        const float* __restrict__ kmn, short* __restrict__ Kb)
{
  __shared__ short KT[64][136];
  int bid = blockIdx.x;                  // 2048 = 32 groups x 64 n-tiles
  int nt = bid & 63, g = bid >> 6;
  int tid = threadIdx.x;
  int d = tid >> 1, half = tid & 1;
  float sc = ksc[(g*128 + d)*64 + nt];
  float mn = kmn[(g*128 + d)*64 + nt];
  #pragma unroll
  for (int j=0;j<2;++j){
    unsigned w = (unsigned)kq[(g*128 + d)*256 + nt*4 + half*2 + j];
    int nbase = (half*2 + j)*16;
    #pragma unroll
    for (int e=0;e<16;++e){
      float v = (float)((w >> (2*e)) & 3u) * sc + mn;
      KT[nbase + e][d] = f2bf(v);
    }
  }
  __syncthreads();
  int n = tid >> 2, c = (tid & 3) * 32;
  const int4* s4 = (const int4*)&KT[n][c];
  int4* d4 = (int4*)(Kb + (g*4352 + nt*64 + n)*128 + c);
  d4[0]=s4[0]; d4[1]=s4[1]; d4[2]=s4[2]; d4[3]=s4[3];
}

// ---------------- 6) dequant 2-bit values -> Vt[d][n] (n<4096) ---------------
__global__ void k_deq_v(const int* __restrict__ vq, const float* __restrict__ vsc,
                        const float* __restrict__ vmn, short* __restrict__ Vt)
{
  __shared__ short VT[128][72];
  int bid = blockIdx.x;                  // 2048
  int nt = bid & 63, g = bid >> 6;
  int tid = threadIdx.x;
  int n = tid >> 2, dp = tid & 3;
  int nglob = nt*64 + n;
  #pragma unroll
  for (int j=0;j<2;++j){
    int dw = dp*2 + j;
    float sc = vsc[(g*4096 + nglob)*2 + (dw>>2)];
    float mn = vmn[(g*4096 + nglob)*2 + (dw>>2)];
    unsigned w = (unsigned)vq[(g*4096 + nglob)*8 + dw];
    #pragma unroll
    for (int e=0;e<16;++e){
      float v = (float)((w >> (2*e)) & 3u) * sc + mn;
      VT[dw*16 + e][n] = f2bf(v);
    }
  }
  __syncthreads();
  int d = tid >> 1, c = (tid & 1) * 32;
  const int4* s4 = (const int4*)&VT[d][c];
  int4* d4 = (int4*)(Vt + (g*128 + d)*4352 + nt*64 + c);
  d4[0]=s4[0]; d4[1]=s4[1]; d4[2]=s4[2]; d4[3]=s4[3];
}

// ---------------- 7) fused flash attention, split-KV (2 blocks/CU) -----------
__global__ __launch_bounds__(256,2) void k_attn(
    const short* __restrict__ Qb, const short* __restrict__ Kb,
    const short* __restrict__ Vt, float* __restrict__ po, float* __restrict__ lp)
{
  __shared__ short Ks[2][64*128];    // 2 x 16 KB
  __shared__ short Vs[2][128*64];    // 2 x 16 KB
  __shared__ short Ps[64*64];        // 8 KB, chunk-XOR swizzled
  int bid = blockIdx.x;              // 512 = kvh(8) x [split(2) x m(8) x b(4)]
  int kvh = bid & 7, y = bid >> 3;
  int split = y & 1, m = (y >> 1) & 7, b = y >> 4;
  int qt = m & 1, hloc = m >> 1;
  int h = kvh*4 + hloc;
  int g = b*8 + kvh;
  int tid = threadIdx.x, w = tid>>6, L = tid&63;
  int lr = L&15, quad = L>>4;
  const short* kbase = Kb + (size_t)g*4352*128;
  const short* vbase = Vt + (size_t)g*128*4352;

  // Q fragments straight from global (each element read exactly once)
  bf16x8 qf[4];
  {
    const short* qrow = Qb + ((size_t)(b*32+h)*128 + qt*64 + w*16 + lr)*128;
    #pragma unroll
    for (int kd=0;kd<4;++kd)
      qf[kd] = *(const bf16x8*)(qrow + (kd*4+quad)*8);
  }

  auto stageKV = [&](int t, int buf){
    #pragma unroll
    for (int i=0;i<4;++i){
      int row = w*16 + i*4 + (L>>4);
      int cl = (L&15) ^ (row&7);
      gl_lds16(kbase + (size_t)(t*64+row)*128 + cl*8, &Ks[buf][(w*16+i*4)*128]);
    }
    #pragma unroll
    for (int i=0;i<4;++i){
      int row = w*32 + i*8 + (L>>3);
      int cl = (L&7) ^ (row&7);
      gl_lds16(vbase + (size_t)row*4352 + t*64 + cl*8, &Vs[buf][(w*32+i*8)*64]);
    }
  };

  int t0 = split*34;
  stageKV(t0, 0);
  __syncthreads();

  float l_part[4] = {0.f,0.f,0.f,0.f};
  f32x4 o_acc[8] = {};
  int q_glob = qt*64 + w*16 + quad*4;

  for (int ti=0; ti<34; ++ti){
    int t = t0 + ti;
    int cur = ti & 1;
    if (ti < 33) stageKV(t+1, cur^1);
    f32x4 s[4] = {};
    #pragma unroll
    for (int kd=0;kd<4;++kd){
      #pragma unroll
      for (int nt=0;nt<4;++nt){
        bf16x8 kf = *(const bf16x8*)&Ks[cur][(nt*16+lr)*128 + (((kd*4+quad)^(lr&7))*8)];
        s[nt] = MFMA16(qf[kd], kf, s[nt]);
      }
    }
    if (t >= 66){                    // causal mask: cols >= 4224 (split 1 only)
      #pragma unroll
      for (int nt=0;nt<4;++nt){
        int jj = t*64 + nt*16 + lr - 4224;
        #pragma unroll
        for (int r=0;r<4;++r)
          if (jj > q_glob + r) s[nt][r] = -1e30f;
      }
    }
    #pragma unroll
    for (int nt=0;nt<4;++nt){
      #pragma unroll
      for (int r=0;r<4;++r){
        float p = exp2f(s[nt][r]);   // Q pre-scaled by log2e/sqrt(D)
        l_part[r] += p;
        int pc = nt*16 + lr;
        Ps[(w*16 + quad*4 + r)*64 + ((((pc>>3) ^ (quad<<1))<<3)) + (pc&7)] = f2bf(p);
      }
    }
    #pragma unroll
    for (int ks=0;ks<2;++ks){
      bf16x8 a = *(const bf16x8*)&Ps[(w*16+lr)*64 + ((((ks*4+quad) ^ (((lr>>2)&3)<<1)))<<3)];
      #pragma unroll
      for (int dt=0;dt<8;++dt){
        bf16x8 vf = *(const bf16x8*)&Vs[cur][(dt*16+lr)*64 + (((ks*4+quad)^(lr&7))*8)];
        o_acc[dt] = MFMA16(a, vf, o_acc[dt]);
      }
    }
    __syncthreads();                 // buffer rotation + DMA drain (one per tile)
  }
  #pragma unroll
  for (int r=0;r<4;++r){
    #pragma unroll
    for (int off=1; off<16; off<<=1)
      l_part[r] += __shfl_xor(l_part[r], off, 64);
  }
  int prow = (b*32+h)*128 + qt*64 + w*16 + quad*4;
  float* pob = po + (size_t)split*16384*128;
  #pragma unroll
  for (int dt=0;dt<8;++dt)
    #pragma unroll
    for (int r=0;r<4;++r)
      pob[(size_t)(prow + r)*128 + dt*16 + lr] = o_acc[dt][r];
  if (lr == 0){
    #pragma unroll
    for (int r=0;r<4;++r) lp[split*16384 + prow + r] = l_part[r];
  }
}

// ---------------- 7b) combine split-KV partials -> attn bf16 -----------------
__global__ void k_att_comb(const float* __restrict__ po, const float* __restrict__ lp,
                           short* __restrict__ attn)
{
  int i = blockIdx.x*256 + threadIdx.x;   // 524288 threads, 4 floats each
  int row = i >> 5, cp = (i & 31) * 4;    // row = (b*32+h)*128 + q
  float4 a = *(const float4*)(po + (size_t)row*128 + cp);
  float4 c = *(const float4*)(po + (size_t)(16384 + row)*128 + cp);
  float inv = 1.0f / (lp[row] + lp[16384 + row]);
  int bb = row >> 12, hh = (row >> 7) & 31, q = row & 127;
  short4 o;
  o.x = f2bf((a.x + c.x) * inv);
  o.y = f2bf((a.y + c.y) * inv);
  o.z = f2bf((a.z + c.z) * inv);
  o.w = f2bf((a.w + c.w) * inv);
  *(short4*)(attn + (size_t)(bb*128 + q)*4096 + hh*128 + cp) = o;
}

// -----------------------------------------------------------------------------
extern "C" void kernel_launch(void* const* d_in, const int* in_sizes, int n_in,
                              void* d_out, int out_size, void* d_ws, size_t ws_size,
                              hipStream_t stream)
{
  const float* hs  = (const float*)d_in[0];
  const float* q_w = (const float*)d_in[1];
  const float* q_b = (const float*)d_in[2];
  const float* k_w = (const float*)d_in[3];
  const float* k_b = (const float*)d_in[4];
  const float* v_w = (const float*)d_in[5];
  const float* v_b = (const float*)d_in[6];
  const float* o_w = (const float*)d_in[7];
  const int*   kq  = (const int*)d_in[8];
  const float* ksc = (const float*)d_in[9];
  const float* kmn = (const float*)d_in[10];
  const float* kf  = (const float*)d_in[11];
  const int*   vq  = (const int*)d_in[12];
  const float* vsc = (const float*)d_in[13];
  const float* vmn = (const float*)d_in[14];
  const float* vf  = (const float*)d_in[15];

  char* w = (char*)d_ws;
  short* hs_b = (short*)w;  w += (size_t)512*4096*2;        //  4.0 MB
  float* qkv  = (float*)w;  w += (size_t)512*6144*4;        // 12.6 MB
  short* Qb   = (short*)w;  w += (size_t)4*32*128*128*2;    //  4.2 MB
  short* Kb   = (short*)w;  w += (size_t)4*8*4352*128*2;    // 35.7 MB
  short* Vt   = (short*)w;  w += (size_t)4*8*4352*128*2;    // 35.7 MB
  short* attn = (short*)w;  w += (size_t)512*4096*2;        //  4.2 MB
  float* scratch = (float*)w;                               // remaining ~84 MB

  // gemm<0> partials (2 slabs, 25.2 MB) alias Kb (35.7 MB), dead before
  // k_rope/k_deq_k rewrite that region. attn split-KV partials and gemm<1>
  // partials (4 slabs, 33.5 MB) live in the scratch region.
  float* P0 = (float*)Kb;
  float* po = scratch;                                      // 2*16384*128*4 = 16.78 MB
  float* lp = scratch + (size_t)2*16384*128;                // 2*16384*4    = 128 KB
  float* P1 = scratch;                                      // reused after att_comb

  k_cast_hs <<<2048, 256, 0, stream>>>(hs, hs_b);
  k_gemm<0> <<<384,  256, 0, stream>>>(hs_b, q_w, k_w, v_w, P0);
  k_comb<0> <<<3072, 256, 0, stream>>>(P0, q_b, k_b, v_b, qkv);
  k_rope    <<<192,  256, 0, stream>>>(qkv, kf, Qb, Kb);
  k_vtrans  <<<64,   256, 0, stream>>>(qkv, vf, Vt);
  k_deq_k   <<<2048, 256, 0, stream>>>(kq, ksc, kmn, Kb);
  k_deq_v   <<<2048, 256, 0, stream>>>(vq, vsc, vmn, Vt);
  k_attn    <<<512,  256, 0, stream>>>(Qb, Kb, Vt, po, lp);
  k_att_comb<<<2048, 256, 0, stream>>>(po, lp, attn);
  k_gemm<1> <<<512,  256, 0, stream>>>(attn, o_w, nullptr, nullptr, P1);
  k_comb<1> <<<2048, 256, 0, stream>>>(P1, nullptr, nullptr, nullptr, (float*)d_out);
}